// Round 1
// baseline (7151.801 us; speedup 1.0000x reference)
//
#include <hip/hip_runtime.h>

#define N_SRC 50000
#define N_DST1 20000
#define N_DST2 10000
#define E1 320000
#define E2 160000
#define T 12
#define C_IN 64
#define HID 16
#define C_OUT 32

// ---- float <-> order-preserving uint encoding for atomicMax on floats ----
__device__ __forceinline__ unsigned enc_f(float f) {
    unsigned u = __float_as_uint(f);
    return (u & 0x80000000u) ? ~u : (u | 0x80000000u);
}
__device__ __forceinline__ float dec_f(unsigned e) {
    unsigned u = (e & 0x80000000u) ? (e & 0x7fffffffu) : ~e;
    return __uint_as_float(u);
}
__device__ __forceinline__ float lrelu(float x, float s) { return x > 0.f ? x : s * x; }

// ---------------- Layer-1 transform: h = x @ W1, el = h.a_l, er = h.a_r ----
// x[n][t][c] = node_feat[t][n][c]  (transpose folded into addressing)
__global__ __launch_bounds__(256) void k_transform1(
    const float* __restrict__ node_feat, const float* __restrict__ W1,
    const float* __restrict__ a_l, const float* __restrict__ a_r,
    float* __restrict__ hs1, float* __restrict__ el1, float* __restrict__ er1)
{
    __shared__ float w[C_IN][HID];
    __shared__ float al[HID], ar[HID];
    int tx = threadIdx.x;
    for (int i = tx; i < C_IN * HID; i += 256) w[i / HID][i % HID] = W1[i];
    if (tx < HID) { al[tx] = a_l[tx]; ar[tx] = a_r[tx]; }
    __syncthreads();
    int n = blockIdx.x * 256 + tx;
    int t = blockIdx.y;
    if (n >= N_SRC) return;
    const float4* xp = reinterpret_cast<const float4*>(node_feat + ((size_t)t * N_SRC + n) * C_IN);
    float h[HID];
#pragma unroll
    for (int o = 0; o < HID; o++) h[o] = 0.f;
#pragma unroll
    for (int c4 = 0; c4 < C_IN / 4; c4++) {
        float4 v = xp[c4];
#pragma unroll
        for (int o = 0; o < HID; o++) {
            h[o] += v.x * w[4 * c4 + 0][o] + v.y * w[4 * c4 + 1][o]
                  + v.z * w[4 * c4 + 2][o] + v.w * w[4 * c4 + 3][o];
        }
    }
    float el = 0.f, er = 0.f;
#pragma unroll
    for (int o = 0; o < HID; o++) { el += h[o] * al[o]; er += h[o] * ar[o]; }
    size_t base = ((size_t)n * T + t) * HID;
    float4* hp = reinterpret_cast<float4*>(hs1 + base);
#pragma unroll
    for (int q = 0; q < HID / 4; q++)
        hp[q] = make_float4(h[4 * q], h[4 * q + 1], h[4 * q + 2], h[4 * q + 3]);
    el1[n * T + t] = el;
    if (n < N_DST1) er1[n * T + t] = er;
}

// ---------------- Layer-2 transform: h2 = h1 @ W2 ------------------------
__global__ __launch_bounds__(256) void k_transform2(
    const float* __restrict__ h1, const float* __restrict__ W2,
    const float* __restrict__ a_l, const float* __restrict__ a_r,
    float* __restrict__ hs2, float* __restrict__ el2, float* __restrict__ er2)
{
    __shared__ float w[HID][C_OUT];
    __shared__ float al[C_OUT], ar[C_OUT];
    int tx = threadIdx.x;
    for (int i = tx; i < HID * C_OUT; i += 256) w[i / C_OUT][i % C_OUT] = W2[i];
    if (tx < C_OUT) { al[tx] = a_l[tx]; ar[tx] = a_r[tx]; }
    __syncthreads();
    int idx = blockIdx.x * 256 + tx;      // over N_DST1*T
    if (idx >= N_DST1 * T) return;
    int n = idx / T;
    const float4* xp = reinterpret_cast<const float4*>(h1 + (size_t)idx * HID);
    float x[HID];
#pragma unroll
    for (int q = 0; q < HID / 4; q++) {
        float4 v = xp[q];
        x[4 * q] = v.x; x[4 * q + 1] = v.y; x[4 * q + 2] = v.z; x[4 * q + 3] = v.w;
    }
    float h[C_OUT];
#pragma unroll
    for (int o = 0; o < C_OUT; o++) h[o] = 0.f;
#pragma unroll
    for (int c = 0; c < HID; c++) {
#pragma unroll
        for (int o = 0; o < C_OUT; o++) h[o] += x[c] * w[c][o];
    }
    float el = 0.f, er = 0.f;
#pragma unroll
    for (int o = 0; o < C_OUT; o++) { el += h[o] * al[o]; er += h[o] * ar[o]; }
    float4* hp = reinterpret_cast<float4*>(hs2 + (size_t)idx * C_OUT);
#pragma unroll
    for (int q = 0; q < C_OUT / 4; q++)
        hp[q] = make_float4(h[4 * q], h[4 * q + 1], h[4 * q + 2], h[4 * q + 3]);
    el2[idx] = el;
    if (n < N_DST2) er2[idx] = er;
}

// ---------------- per-edge segment max (atomicMax on encoded float) -------
__global__ __launch_bounds__(256) void k_edge_max(
    const int* __restrict__ src_idx, const int* __restrict__ dst_idx,
    const float* __restrict__ el, const float* __restrict__ er,
    unsigned* __restrict__ menc, int E)
{
    int e = blockIdx.x * 256 + threadIdx.x;
    if (e >= E) return;
    int s = src_idx[e], d = dst_idx[e];
    const float4* elp = reinterpret_cast<const float4*>(el + (size_t)s * T);
    const float4* erp = reinterpret_cast<const float4*>(er + (size_t)d * T);
#pragma unroll
    for (int q = 0; q < T / 4; q++) {
        float4 a = elp[q], b = erp[q];
        float v0 = lrelu(a.x + b.x, 0.2f), v1 = lrelu(a.y + b.y, 0.2f);
        float v2 = lrelu(a.z + b.z, 0.2f), v3 = lrelu(a.w + b.w, 0.2f);
        atomicMax(menc + (size_t)d * T + 4 * q + 0, enc_f(v0));
        atomicMax(menc + (size_t)d * T + 4 * q + 1, enc_f(v1));
        atomicMax(menc + (size_t)d * T + 4 * q + 2, enc_f(v2));
        atomicMax(menc + (size_t)d * T + 4 * q + 3, enc_f(v3));
    }
}

// ---------------- per-(edge,t) exp + accumulate numerator & denominator ---
template <int O>
__global__ __launch_bounds__(256) void k_edge_acc(
    const int* __restrict__ src_idx, const int* __restrict__ dst_idx,
    const float* __restrict__ ew,
    const float* __restrict__ el, const float* __restrict__ er,
    const unsigned* __restrict__ menc, const float* __restrict__ hs,
    float* __restrict__ s_sum, float* __restrict__ acc, int E)
{
    int tid = blockIdx.x * 256 + threadIdx.x;
    if (tid >= E * T) return;
    int e = tid / T, t = tid - e * T;
    int s = src_idx[e], d = dst_idx[e];
    float lg = lrelu(el[(size_t)s * T + t] + er[(size_t)d * T + t], 0.2f);
    float m = dec_f(menc[(size_t)d * T + t]);
    float ex = __expf(lg - m);
    atomicAdd(s_sum + (size_t)d * T + t, ex);
    float coef = ex * ew[e];
    const float4* hp = reinterpret_cast<const float4*>(hs + ((size_t)s * T + t) * O);
    float* ap = acc + ((size_t)d * T + t) * O;
#pragma unroll
    for (int q = 0; q < O / 4; q++) {
        float4 hv = hp[q];
        atomicAdd(ap + 4 * q + 0, coef * hv.x);
        atomicAdd(ap + 4 * q + 1, coef * hv.y);
        atomicAdd(ap + 4 * q + 2, coef * hv.z);
        atomicAdd(ap + 4 * q + 3, coef * hv.w);
    }
}

// ---------------- finalize layer-1: h1 = lrelu(acc/s, 0.01) in place ------
__global__ __launch_bounds__(256) void k_finalize1(
    float* __restrict__ acc, const float* __restrict__ s_sum)
{
    int i = blockIdx.x * 256 + threadIdx.x;
    if (i >= N_DST1 * T * HID) return;
    int nt = i / HID;
    float v = acc[i] / (s_sum[nt] + 1e-9f);
    acc[i] = lrelu(v, 0.01f);
}

// ---------------- finalize layer-2 + transpose to [T, N, O] ---------------
__global__ __launch_bounds__(256) void k_finalize2(
    const float* __restrict__ acc, const float* __restrict__ s_sum,
    float* __restrict__ out)
{
    int i = blockIdx.x * 256 + threadIdx.x;
    if (i >= T * N_DST2 * C_OUT) return;
    int o = i & 31;
    int tn = i >> 5;
    int n = tn % N_DST2;
    int t = tn / N_DST2;
    float v = acc[((size_t)n * T + t) * C_OUT + o] / (s_sum[n * T + t] + 1e-9f);
    out[i] = lrelu(v, 0.01f);
}

extern "C" void kernel_launch(void* const* d_in, const int* in_sizes, int n_in,
                              void* d_out, int out_size, void* d_ws, size_t ws_size,
                              hipStream_t stream)
{
    const float* node_feat = (const float*)d_in[0];
    const int*   esrc1     = (const int*)d_in[1];
    const int*   edst1     = (const int*)d_in[2];
    const float* ew1       = (const float*)d_in[3];
    const int*   esrc2     = (const int*)d_in[4];
    const int*   edst2     = (const int*)d_in[5];
    const float* ew2       = (const float*)d_in[6];
    const float* W1        = (const float*)d_in[7];
    const float* a_l1      = (const float*)d_in[8];
    const float* a_r1      = (const float*)d_in[9];
    const float* W2        = (const float*)d_in[10];
    const float* a_l2      = (const float*)d_in[11];
    const float* a_r2      = (const float*)d_in[12];
    float* out = (float*)d_out;

    // ---- workspace layout (floats) ----
    float* ws = (float*)d_ws;
    float*    hs1  = ws;                       // 9,600,000  [N_SRC][T][HID]
    float*    el1  = hs1 + 9600000;            //   600,000  [N_SRC][T]
    float*    er1  = el1 + 600000;             //   240,000  [N_DST1][T]
    unsigned* m1   = (unsigned*)(er1 + 240000);//   240,000  [N_DST1][T]
    float*    s1   = (float*)m1 + 240000;      //   240,000
    float*    acc1 = s1 + 240000;              // 3,840,000  [N_DST1][T][HID] -> becomes h1
    float*    hs2  = acc1 + 3840000;           // 7,680,000  [N_DST1][T][C_OUT]
    float*    el2  = hs2 + 7680000;            //   240,000
    float*    er2  = el2 + 240000;             //   120,000  [N_DST2][T]
    unsigned* m2   = (unsigned*)(er2 + 120000);//   120,000
    float*    s2   = (float*)m2 + 120000;      //   120,000
    float*    acc2 = s2 + 120000;              // 3,840,000  [N_DST2][T][C_OUT]
    // total: 26,880,000 floats = 107.5 MB

    // zero the reduction buffers every call (harness does not re-poison)
    hipMemsetAsync(m1, 0, (size_t)(240000 + 240000 + 3840000) * 4, stream);
    hipMemsetAsync(m2, 0, (size_t)(120000 + 120000 + 3840000) * 4, stream);

    // ---- layer 1 ----
    {
        dim3 g((N_SRC + 255) / 256, T);
        k_transform1<<<g, 256, 0, stream>>>(node_feat, W1, a_l1, a_r1, hs1, el1, er1);
    }
    k_edge_max<<<(E1 + 255) / 256, 256, 0, stream>>>(esrc1, edst1, el1, er1, m1, E1);
    k_edge_acc<HID><<<(E1 * T + 255) / 256, 256, 0, stream>>>(
        esrc1, edst1, ew1, el1, er1, m1, hs1, s1, acc1, E1);
    k_finalize1<<<(N_DST1 * T * HID + 255) / 256, 256, 0, stream>>>(acc1, s1);

    // ---- layer 2 (features = acc1, i.e. h1) ----
    k_transform2<<<(N_DST1 * T + 255) / 256, 256, 0, stream>>>(
        acc1, W2, a_l2, a_r2, hs2, el2, er2);
    k_edge_max<<<(E2 + 255) / 256, 256, 0, stream>>>(esrc2, edst2, el2, er2, m2, E2);
    k_edge_acc<C_OUT><<<(E2 * T + 255) / 256, 256, 0, stream>>>(
        esrc2, edst2, ew2, el2, er2, m2, hs2, s2, acc2, E2);
    k_finalize2<<<(T * N_DST2 * C_OUT + 255) / 256, 256, 0, stream>>>(acc2, s2, out);
}

// Round 2
// 583.829 us; speedup vs baseline: 12.2498x; 12.2498x over previous
//
#include <hip/hip_runtime.h>

#define N_SRC 50000
#define N_DST1 20000
#define N_DST2 10000
#define E1 320000
#define E2 160000
#define T 12
#define C_IN 64
#define HID 16
#define C_OUT 32

__device__ __forceinline__ float lrelu(float x, float s) { return x > 0.f ? x : s * x; }

// ---------------- Layer-1 transform: h = x @ W1, el = h.a_l, er = h.a_r ----
__global__ __launch_bounds__(256) void k_transform1(
    const float* __restrict__ node_feat, const float* __restrict__ W1,
    const float* __restrict__ a_l, const float* __restrict__ a_r,
    float* __restrict__ hs1, float* __restrict__ el1, float* __restrict__ er1)
{
    __shared__ float w[C_IN][HID];
    __shared__ float al[HID], ar[HID];
    int tx = threadIdx.x;
    for (int i = tx; i < C_IN * HID; i += 256) w[i / HID][i % HID] = W1[i];
    if (tx < HID) { al[tx] = a_l[tx]; ar[tx] = a_r[tx]; }
    __syncthreads();
    int n = blockIdx.x * 256 + tx;
    int t = blockIdx.y;
    if (n >= N_SRC) return;
    const float4* xp = reinterpret_cast<const float4*>(node_feat + ((size_t)t * N_SRC + n) * C_IN);
    float h[HID];
#pragma unroll
    for (int o = 0; o < HID; o++) h[o] = 0.f;
#pragma unroll
    for (int c4 = 0; c4 < C_IN / 4; c4++) {
        float4 v = xp[c4];
#pragma unroll
        for (int o = 0; o < HID; o++) {
            h[o] += v.x * w[4 * c4 + 0][o] + v.y * w[4 * c4 + 1][o]
                  + v.z * w[4 * c4 + 2][o] + v.w * w[4 * c4 + 3][o];
        }
    }
    float el = 0.f, er = 0.f;
#pragma unroll
    for (int o = 0; o < HID; o++) { el += h[o] * al[o]; er += h[o] * ar[o]; }
    size_t base = ((size_t)n * T + t) * HID;
    float4* hp = reinterpret_cast<float4*>(hs1 + base);
#pragma unroll
    for (int q = 0; q < HID / 4; q++)
        hp[q] = make_float4(h[4 * q], h[4 * q + 1], h[4 * q + 2], h[4 * q + 3]);
    el1[n * T + t] = el;
    if (n < N_DST1) er1[n * T + t] = er;
}

// ---------------- Layer-2 transform: h2 = h1 @ W2 ------------------------
__global__ __launch_bounds__(256) void k_transform2(
    const float* __restrict__ h1, const float* __restrict__ W2,
    const float* __restrict__ a_l, const float* __restrict__ a_r,
    float* __restrict__ hs2, float* __restrict__ el2, float* __restrict__ er2)
{
    __shared__ float w[HID][C_OUT];
    __shared__ float al[C_OUT], ar[C_OUT];
    int tx = threadIdx.x;
    for (int i = tx; i < HID * C_OUT; i += 256) w[i / C_OUT][i % C_OUT] = W2[i];
    if (tx < C_OUT) { al[tx] = a_l[tx]; ar[tx] = a_r[tx]; }
    __syncthreads();
    int idx = blockIdx.x * 256 + tx;      // over N_DST1*T
    if (idx >= N_DST1 * T) return;
    int n = idx / T;
    const float4* xp = reinterpret_cast<const float4*>(h1 + (size_t)idx * HID);
    float x[HID];
#pragma unroll
    for (int q = 0; q < HID / 4; q++) {
        float4 v = xp[q];
        x[4 * q] = v.x; x[4 * q + 1] = v.y; x[4 * q + 2] = v.z; x[4 * q + 3] = v.w;
    }
    float h[C_OUT];
#pragma unroll
    for (int o = 0; o < C_OUT; o++) h[o] = 0.f;
#pragma unroll
    for (int c = 0; c < HID; c++) {
#pragma unroll
        for (int o = 0; o < C_OUT; o++) h[o] += x[c] * w[c][o];
    }
    float el = 0.f, er = 0.f;
#pragma unroll
    for (int o = 0; o < C_OUT; o++) { el += h[o] * al[o]; er += h[o] * ar[o]; }
    float4* hp = reinterpret_cast<float4*>(hs2 + (size_t)idx * C_OUT);
#pragma unroll
    for (int q = 0; q < C_OUT / 4; q++)
        hp[q] = make_float4(h[4 * q], h[4 * q + 1], h[4 * q + 2], h[4 * q + 3]);
    el2[idx] = el;
    if (n < N_DST2) er2[idx] = er;
}

// ---------------- CSR build: histogram, scan, scatter ---------------------
__global__ __launch_bounds__(256) void k_hist(
    const int* __restrict__ dst, int* __restrict__ cnt, int E)
{
    int e = blockIdx.x * 256 + threadIdx.x;
    if (e < E) atomicAdd(&cnt[dst[e]], 1);
}

// single-block exclusive scan: off[0]=0, off[i+1]=sum(cnt[0..i])
__global__ __launch_bounds__(256) void k_scan(
    const int* __restrict__ cnt, int* __restrict__ off, int N)
{
    __shared__ int buf[256];
    __shared__ int carry;
    int tx = threadIdx.x;
    if (tx == 0) { carry = 0; off[0] = 0; }
    __syncthreads();
    for (int base = 0; base < N; base += 256) {
        int i = base + tx;
        int v = (i < N) ? cnt[i] : 0;
        buf[tx] = v;
        __syncthreads();
#pragma unroll
        for (int d = 1; d < 256; d <<= 1) {
            int tv = (tx >= d) ? buf[tx - d] : 0;
            __syncthreads();
            buf[tx] += tv;
            __syncthreads();
        }
        if (i < N) off[i + 1] = carry + buf[tx];
        __syncthreads();
        if (tx == 255) carry += buf[255];
        __syncthreads();
    }
}

__global__ __launch_bounds__(256) void k_scatter(
    const int* __restrict__ src, const int* __restrict__ dst,
    const float* __restrict__ ew, int* __restrict__ cursor,
    int* __restrict__ s_srt, float* __restrict__ w_srt, int E)
{
    int e = blockIdx.x * 256 + threadIdx.x;
    if (e >= E) return;
    int d = dst[e];
    int p = atomicAdd(&cursor[d], 1);
    s_srt[p] = src[e];
    w_srt[p] = ew[e];
}

// ---------------- dst-centric aggregation: no atomics ---------------------
// one thread per (dst, t, o); o fastest. O*T is a multiple of 64 for both
// layers, so every wave sees a single dst -> no degree divergence.
template <int O, bool TR>
__global__ __launch_bounds__(256) void k_aggregate(
    const int* __restrict__ off, const int* __restrict__ s_srt,
    const float* __restrict__ w_srt,
    const float* __restrict__ el, const float* __restrict__ er,
    const float* __restrict__ hs, float* __restrict__ outp, int n_dst)
{
    int tid = blockIdx.x * 256 + threadIdx.x;
    if (tid >= n_dst * T * O) return;
    int o = tid % O;
    int t = (tid / O) % T;
    int d = tid / (O * T);
    int start = off[d], end = off[d + 1];
    float erv = er[d * T + t];
    float m = -1e30f;
    for (int i = start; i < end; i++) {
        int s = s_srt[i];
        float lg = lrelu(el[s * T + t] + erv, 0.2f);
        m = fmaxf(m, lg);
    }
    float num = 0.f, den = 0.f;
    for (int i = start; i < end; i++) {
        int s = s_srt[i];
        float lg = lrelu(el[s * T + t] + erv, 0.2f);
        float ex = __expf(lg - m);
        den += ex;
        num += ex * w_srt[i] * hs[((size_t)s * T + t) * O + o];
    }
    float v = lrelu(num / (den + 1e-9f), 0.01f);
    if (TR) outp[((size_t)t * n_dst + d) * O + o] = v;
    else    outp[((size_t)d * T + t) * O + o] = v;
}

extern "C" void kernel_launch(void* const* d_in, const int* in_sizes, int n_in,
                              void* d_out, int out_size, void* d_ws, size_t ws_size,
                              hipStream_t stream)
{
    const float* node_feat = (const float*)d_in[0];
    const int*   esrc1     = (const int*)d_in[1];
    const int*   edst1     = (const int*)d_in[2];
    const float* ew1       = (const float*)d_in[3];
    const int*   esrc2     = (const int*)d_in[4];
    const int*   edst2     = (const int*)d_in[5];
    const float* ew2       = (const float*)d_in[6];
    const float* W1        = (const float*)d_in[7];
    const float* a_l1      = (const float*)d_in[8];
    const float* a_r1      = (const float*)d_in[9];
    const float* W2        = (const float*)d_in[10];
    const float* a_l2      = (const float*)d_in[11];
    const float* a_r2      = (const float*)d_in[12];
    float* out = (float*)d_out;

    // ---- workspace layout ----
    float* ws = (float*)d_ws;
    float* hs1 = ws;                    //  9,600,000  [N_SRC][T][HID]
    float* el1 = hs1 + 9600000;         //    600,000  [N_SRC][T]
    float* er1 = el1 + 600000;          //    240,000  [N_DST1][T]
    float* h1  = er1 + 240000;          //  3,840,000  [N_DST1][T][HID]
    float* hs2 = h1 + 3840000;          //  7,680,000  [N_DST1][T][C_OUT]
    float* el2 = hs2 + 7680000;         //    240,000  [N_DST1][T]
    float* er2 = el2 + 240000;          //    120,000  [N_DST2][T]
    float* w_srt1 = er2 + 120000;       //    320,000
    float* w_srt2 = w_srt1 + E1;        //    160,000
    int* ip = (int*)(w_srt2 + E2);
    int* cnt1    = ip;                  //  20,000
    int* off1    = cnt1 + N_DST1;       //  20,001
    int* cur1    = off1 + N_DST1 + 1;   //  20,000
    int* s_srt1  = cur1 + N_DST1;       // 320,000
    int* cnt2    = s_srt1 + E1;         //  10,000
    int* off2    = cnt2 + N_DST2;       //  10,001
    int* cur2    = off2 + N_DST2 + 1;   //  10,000
    int* s_srt2  = cur2 + N_DST2;       // 160,000
    // total ~= 91.6 MB

    // zero the histograms (harness does not re-poison ws between replays)
    hipMemsetAsync(cnt1, 0, N_DST1 * sizeof(int), stream);
    hipMemsetAsync(cnt2, 0, N_DST2 * sizeof(int), stream);

    // ---- CSR builds (independent of feature data) ----
    k_hist<<<(E1 + 255) / 256, 256, 0, stream>>>(edst1, cnt1, E1);
    k_scan<<<1, 256, 0, stream>>>(cnt1, off1, N_DST1);
    hipMemcpyAsync(cur1, off1, N_DST1 * sizeof(int), hipMemcpyDeviceToDevice, stream);
    k_scatter<<<(E1 + 255) / 256, 256, 0, stream>>>(esrc1, edst1, ew1, cur1, s_srt1, w_srt1, E1);

    k_hist<<<(E2 + 255) / 256, 256, 0, stream>>>(edst2, cnt2, E2);
    k_scan<<<1, 256, 0, stream>>>(cnt2, off2, N_DST2);
    hipMemcpyAsync(cur2, off2, N_DST2 * sizeof(int), hipMemcpyDeviceToDevice, stream);
    k_scatter<<<(E2 + 255) / 256, 256, 0, stream>>>(esrc2, edst2, ew2, cur2, s_srt2, w_srt2, E2);

    // ---- layer 1 ----
    {
        dim3 g((N_SRC + 255) / 256, T);
        k_transform1<<<g, 256, 0, stream>>>(node_feat, W1, a_l1, a_r1, hs1, el1, er1);
    }
    k_aggregate<HID, false><<<(N_DST1 * T * HID + 255) / 256, 256, 0, stream>>>(
        off1, s_srt1, w_srt1, el1, er1, hs1, h1, N_DST1);

    // ---- layer 2 ----
    k_transform2<<<(N_DST1 * T + 255) / 256, 256, 0, stream>>>(
        h1, W2, a_l2, a_r2, hs2, el2, er2);
    k_aggregate<C_OUT, true><<<(N_DST2 * T * C_OUT + 255) / 256, 256, 0, stream>>>(
        off2, s_srt2, w_srt2, el2, er2, hs2, out, N_DST2);
}

// Round 3
// 371.208 us; speedup vs baseline: 19.2663x; 1.5728x over previous
//
#include <hip/hip_runtime.h>

#define N_SRC 50000
#define N_DST1 20000
#define N_DST2 10000
#define E1 320000
#define E2 160000
#define T 12
#define C_IN 64
#define HID 16
#define C_OUT 32

__device__ __forceinline__ float lrelu(float x, float s) { return x > 0.f ? x : s * x; }

// ---------------- Layer-1 transform: h = x @ W1, el = h.a_l, er = h.a_r ----
__global__ __launch_bounds__(256) void k_transform1(
    const float* __restrict__ node_feat, const float* __restrict__ W1,
    const float* __restrict__ a_l, const float* __restrict__ a_r,
    float* __restrict__ hs1, float* __restrict__ el1, float* __restrict__ er1)
{
    __shared__ float w[C_IN][HID];
    __shared__ float al[HID], ar[HID];
    int tx = threadIdx.x;
    for (int i = tx; i < C_IN * HID; i += 256) w[i / HID][i % HID] = W1[i];
    if (tx < HID) { al[tx] = a_l[tx]; ar[tx] = a_r[tx]; }
    __syncthreads();
    int n = blockIdx.x * 256 + tx;
    int t = blockIdx.y;
    if (n >= N_SRC) return;
    const float4* xp = reinterpret_cast<const float4*>(node_feat + ((size_t)t * N_SRC + n) * C_IN);
    float h[HID];
#pragma unroll
    for (int o = 0; o < HID; o++) h[o] = 0.f;
#pragma unroll
    for (int c4 = 0; c4 < C_IN / 4; c4++) {
        float4 v = xp[c4];
#pragma unroll
        for (int o = 0; o < HID; o++) {
            h[o] += v.x * w[4 * c4 + 0][o] + v.y * w[4 * c4 + 1][o]
                  + v.z * w[4 * c4 + 2][o] + v.w * w[4 * c4 + 3][o];
        }
    }
    float el = 0.f, er = 0.f;
#pragma unroll
    for (int o = 0; o < HID; o++) { el += h[o] * al[o]; er += h[o] * ar[o]; }
    size_t base = ((size_t)n * T + t) * HID;
    float4* hp = reinterpret_cast<float4*>(hs1 + base);
#pragma unroll
    for (int q = 0; q < HID / 4; q++)
        hp[q] = make_float4(h[4 * q], h[4 * q + 1], h[4 * q + 2], h[4 * q + 3]);
    el1[n * T + t] = el;
    if (n < N_DST1) er1[n * T + t] = er;
}

// ---------------- CSR build ----------------------------------------------
__global__ __launch_bounds__(256) void k_hist(
    const int* __restrict__ dst, int* __restrict__ cnt, int E)
{
    int e = blockIdx.x * 256 + threadIdx.x;
    if (e < E) atomicAdd(&cnt[dst[e]], 1);
}

// single-block scan: per-thread serial chunk + block scan of partials.
// writes off[0..N] and cur[0..N-1] (= off[0..N-1]).
__global__ __launch_bounds__(256) void k_scan(
    const int* __restrict__ cnt, int* __restrict__ off, int* __restrict__ cur, int N)
{
    __shared__ int part[256];
    int tx = threadIdx.x;
    int CH = (N + 255) / 256;
    int base = tx * CH;
    int p = 0;
    for (int j = 0; j < CH; j++) { int i = base + j; if (i < N) p += cnt[i]; }
    part[tx] = p;
    __syncthreads();
#pragma unroll
    for (int d = 1; d < 256; d <<= 1) {
        int v = (tx >= d) ? part[tx - d] : 0;
        __syncthreads();
        part[tx] += v;
        __syncthreads();
    }
    int run = (tx == 0) ? 0 : part[tx - 1];
    if (tx == 0) off[0] = 0;
    for (int j = 0; j < CH; j++) {
        int i = base + j;
        if (i < N) { cur[i] = run; run += cnt[i]; off[i + 1] = run; }
    }
}

__global__ __launch_bounds__(256) void k_scatter(
    const int* __restrict__ src, const int* __restrict__ dst,
    const float* __restrict__ ew, int* __restrict__ cursor,
    int* __restrict__ s_srt, float* __restrict__ w_srt, int E)
{
    int e = blockIdx.x * 256 + threadIdx.x;
    if (e >= E) return;
    int d = dst[e];
    int p = atomicAdd(&cursor[d], 1);
    s_srt[p] = src[e];
    w_srt[p] = ew[e];
}

// ---------------- per-(dst,t) softmax: coef = exp(lg-m)*ew, den ----------
__global__ __launch_bounds__(256) void k_coef(
    const int* __restrict__ off, const int* __restrict__ s_srt,
    const float* __restrict__ w_srt,
    const float* __restrict__ el, const float* __restrict__ er,
    float* __restrict__ coef, float* __restrict__ den_out, int n_dst)
{
    int tid = blockIdx.x * 256 + threadIdx.x;
    if (tid >= n_dst * T) return;
    int t = tid % T;
    int d = tid / T;
    int start = off[d], end = off[d + 1];
    float erv = er[tid];
    float m = -1e30f;
    for (int i = start; i < end; i++)
        m = fmaxf(m, lrelu(el[s_srt[i] * T + t] + erv, 0.2f));
    float den = 0.f;
    for (int i = start; i < end; i++) {
        float ex = __expf(lrelu(el[s_srt[i] * T + t] + erv, 0.2f) - m);
        den += ex;
        coef[(size_t)i * T + t] = ex * w_srt[i];
    }
    den_out[tid] = den;
}

// ---------------- 16-wide aggregation: one pass, float4, no atomics ------
// tid = ((d*T + t)*4 + o4); 4 lanes cover one (d,t) row of 16 floats.
template <bool ACT>
__global__ __launch_bounds__(256) void k_agg16(
    const int* __restrict__ off, const int* __restrict__ s_srt,
    const float* __restrict__ coef, const float* __restrict__ den,
    const float* __restrict__ hs, float* __restrict__ outp, int n_dst)
{
    int tid = blockIdx.x * 256 + threadIdx.x;
    if (tid >= n_dst * T * 4) return;
    int o4 = tid & 3;
    int dt = tid >> 2;
    int t = dt % T;
    int start = off[dt / T], end = off[dt / T + 1];
    float4 num = make_float4(0.f, 0.f, 0.f, 0.f);
    for (int i = start; i < end; i++) {
        float c = coef[(size_t)i * T + t];
        int s = s_srt[i];
        float4 hv = *reinterpret_cast<const float4*>(hs + ((size_t)s * T + t) * HID + o4 * 4);
        num.x += c * hv.x; num.y += c * hv.y; num.z += c * hv.z; num.w += c * hv.w;
    }
    float inv = 1.f / (den[dt] + 1e-9f);
    float4 v = make_float4(num.x * inv, num.y * inv, num.z * inv, num.w * inv);
    if (ACT) {
        v.x = lrelu(v.x, 0.01f); v.y = lrelu(v.y, 0.01f);
        v.z = lrelu(v.z, 0.01f); v.w = lrelu(v.w, 0.01f);
    }
    *reinterpret_cast<float4*>(outp + (size_t)dt * HID + o4 * 4) = v;
}

// ---------------- wl2 = W2 @ a_l2, wr2 = W2 @ a_r2 ------------------------
__global__ __launch_bounds__(64) void k_wvec(
    const float* __restrict__ W2, const float* __restrict__ a_l2,
    const float* __restrict__ a_r2, float* __restrict__ wl2, float* __restrict__ wr2)
{
    int tx = threadIdx.x;
    if (tx >= 32) return;
    int c = tx & 15;
    const float* a = (tx < 16) ? a_l2 : a_r2;
    float s = 0.f;
    for (int o = 0; o < C_OUT; o++) s += W2[c * C_OUT + o] * a[o];
    if (tx < 16) wl2[c] = s; else wr2[c] = s;
}

// ---------------- el2/er2 directly from h1 -------------------------------
__global__ __launch_bounds__(256) void k_el2(
    const float* __restrict__ h1, const float* __restrict__ wl2,
    const float* __restrict__ wr2, float* __restrict__ el2, float* __restrict__ er2)
{
    int tid = blockIdx.x * 256 + threadIdx.x;
    if (tid >= N_DST1 * T) return;
    int n = tid / T;
    const float4* hp = reinterpret_cast<const float4*>(h1 + (size_t)tid * HID);
    float el = 0.f, er = 0.f;
#pragma unroll
    for (int q = 0; q < 4; q++) {
        float4 hv = hp[q];
        el += hv.x * wl2[4 * q] + hv.y * wl2[4 * q + 1] + hv.z * wl2[4 * q + 2] + hv.w * wl2[4 * q + 3];
        er += hv.x * wr2[4 * q] + hv.y * wr2[4 * q + 1] + hv.z * wr2[4 * q + 2] + hv.w * wr2[4 * q + 3];
    }
    el2[tid] = el;
    if (n < N_DST2) er2[tid] = er;
}

// ---------------- final: out[t][d][o] = lrelu(agg2[d][t][:] @ W2) ---------
__global__ __launch_bounds__(256) void k_final2(
    const float* __restrict__ agg2, const float* __restrict__ W2,
    float* __restrict__ out)
{
    __shared__ float w[HID][C_OUT];
    int tx = threadIdx.x;
    for (int i = tx; i < HID * C_OUT; i += 256) w[i / C_OUT][i % C_OUT] = W2[i];
    __syncthreads();
    int tid = blockIdx.x * 256 + tx;
    if (tid >= N_DST2 * T * C_OUT) return;
    int o = tid & 31;
    int dt = tid >> 5;
    int t = dt % T;
    int d = dt / T;
    const float4* ap = reinterpret_cast<const float4*>(agg2 + (size_t)dt * HID);
    float s = 0.f;
#pragma unroll
    for (int q = 0; q < 4; q++) {
        float4 av = ap[q];
        s += av.x * w[4 * q][o] + av.y * w[4 * q + 1][o] + av.z * w[4 * q + 2][o] + av.w * w[4 * q + 3][o];
    }
    out[((size_t)t * N_DST2 + d) * C_OUT + o] = lrelu(s, 0.01f);
}

extern "C" void kernel_launch(void* const* d_in, const int* in_sizes, int n_in,
                              void* d_out, int out_size, void* d_ws, size_t ws_size,
                              hipStream_t stream)
{
    const float* node_feat = (const float*)d_in[0];
    const int*   esrc1     = (const int*)d_in[1];
    const int*   edst1     = (const int*)d_in[2];
    const float* ew1       = (const float*)d_in[3];
    const int*   esrc2     = (const int*)d_in[4];
    const int*   edst2     = (const int*)d_in[5];
    const float* ew2       = (const float*)d_in[6];
    const float* W1        = (const float*)d_in[7];
    const float* a_l1      = (const float*)d_in[8];
    const float* a_r1      = (const float*)d_in[9];
    const float* W2        = (const float*)d_in[10];
    const float* a_l2      = (const float*)d_in[11];
    const float* a_r2      = (const float*)d_in[12];
    float* out = (float*)d_out;

    // ---- workspace layout (floats) ----
    float* ws = (float*)d_ws;
    float* hs1   = ws;                  //  9,600,000  [N_SRC][T][HID]
    float* el1   = hs1 + 9600000;       //    600,000  [N_SRC][T]
    float* er1   = el1 + 600000;        //    240,000  [N_DST1][T]
    float* h1    = er1 + 240000;        //  3,840,000  [N_DST1][T][HID]
    float* el2   = h1 + 3840000;        //    240,000  [N_DST1][T]
    float* er2   = el2 + 240000;        //    120,000  [N_DST2][T]
    float* coef1 = er2 + 120000;        //  3,840,000  [E1][T]
    float* den1  = coef1 + 3840000;     //    240,000  [N_DST1][T]
    float* coef2 = den1 + 240000;       //  1,920,000  [E2][T]
    float* den2  = coef2 + 1920000;     //    120,000  [N_DST2][T]
    float* agg2  = den2 + 120000;       //  1,920,000  [N_DST2][T][HID]
    float* w_srt1 = agg2 + 1920000;     //    320,000
    float* w_srt2 = w_srt1 + E1;        //    160,000
    float* wl2   = w_srt2 + E2;         //         16
    float* wr2   = wl2 + 16;            //         16
    int* ip = (int*)(wr2 + 16);
    int* cnt1   = ip;                   //  20,000
    int* off1   = cnt1 + N_DST1;        //  20,001
    int* cur1   = off1 + N_DST1 + 1;    //  20,000
    int* s_srt1 = cur1 + N_DST1;        // 320,000
    int* cnt2   = s_srt1 + E1;          //  10,000
    int* off2   = cnt2 + N_DST2;        //  10,001
    int* cur2   = off2 + N_DST2 + 1;    //  10,000
    int* s_srt2 = cur2 + N_DST2;        // 160,000
    // total ~= 93 MB

    hipMemsetAsync(cnt1, 0, N_DST1 * sizeof(int), stream);
    hipMemsetAsync(cnt2, 0, N_DST2 * sizeof(int), stream);

    // ---- CSR builds ----
    k_hist<<<(E1 + 255) / 256, 256, 0, stream>>>(edst1, cnt1, E1);
    k_scan<<<1, 256, 0, stream>>>(cnt1, off1, cur1, N_DST1);
    k_scatter<<<(E1 + 255) / 256, 256, 0, stream>>>(esrc1, edst1, ew1, cur1, s_srt1, w_srt1, E1);

    k_hist<<<(E2 + 255) / 256, 256, 0, stream>>>(edst2, cnt2, E2);
    k_scan<<<1, 256, 0, stream>>>(cnt2, off2, cur2, N_DST2);
    k_scatter<<<(E2 + 255) / 256, 256, 0, stream>>>(esrc2, edst2, ew2, cur2, s_srt2, w_srt2, E2);

    k_wvec<<<1, 64, 0, stream>>>(W2, a_l2, a_r2, wl2, wr2);

    // ---- layer 1 ----
    {
        dim3 g((N_SRC + 255) / 256, T);
        k_transform1<<<g, 256, 0, stream>>>(node_feat, W1, a_l1, a_r1, hs1, el1, er1);
    }
    k_coef<<<(N_DST1 * T + 255) / 256, 256, 0, stream>>>(
        off1, s_srt1, w_srt1, el1, er1, coef1, den1, N_DST1);
    k_agg16<true><<<(N_DST1 * T * 4 + 255) / 256, 256, 0, stream>>>(
        off1, s_srt1, coef1, den1, hs1, h1, N_DST1);

    // ---- layer 2 (aggregate h1 in HID space, then one small GEMM) ----
    k_el2<<<(N_DST1 * T + 255) / 256, 256, 0, stream>>>(h1, wl2, wr2, el2, er2);
    k_coef<<<(N_DST2 * T + 255) / 256, 256, 0, stream>>>(
        off2, s_srt2, w_srt2, el2, er2, coef2, den2, N_DST2);
    k_agg16<false><<<(N_DST2 * T * 4 + 255) / 256, 256, 0, stream>>>(
        off2, s_srt2, coef2, den2, h1, agg2, N_DST2);
    k_final2<<<(N_DST2 * T * C_OUT + 255) / 256, 256, 0, stream>>>(agg2, W2, out);
}